// Round 13
// baseline (810.827 us; speedup 1.0000x reference)
//
#include <hip/hip_runtime.h>
#include <hip/hip_cooperative_groups.h>

namespace cg = cooperative_groups;

#define F1260 1260

__device__ __forceinline__ float leakyf(float x) { return x >= 0.f ? x : 0.2f * x; }
__device__ __forceinline__ float eluf(float x) { return x > 0.f ? x : expm1f(x); }
__device__ __forceinline__ float sigmoidf(float x) { return 1.f / (1.f + __expf(-x)); }
// fast tanh: exact saturation, ~1e-6 abs err
__device__ __forceinline__ float tanh_fast(float x) { return 1.f - 2.f / (__expf(2.f * x) + 1.f); }

// ================= fused cooperative path =================
// Grid G=1024 blocks x 128 thr (4 blocks/CU -- half the measured-resident
// 8/CU for this shape => co-residency guaranteed, no grid.sync deadlock).
// Phase S: each block computes channel stats for its 32-sample slab (x read
//   ONCE from HBM; slab stays L3-resident). Partials channel-major.
// sync -> Phase R: blocks 0..83 reduce 1024 partials each.
// sync -> Phase P: block 0 finalizes BN + adj + WB folds (the old kB).
// sync -> Phase C: grid-stride 2 groups/block of the r12 kC body -- x now
//   L3-warm from phase S (the whole point: kill the 84 MB HBM re-fetch and
//   the separate kA kernel that fought the poison-fill writeback).
// ws: partials [84][1024] @0; totals[84] @86016; pb @86272 (r12 layout).
#define FG 1024
#define TOT_OFF 86016
#define FPB_OFF 86272
#define RS 252

struct KP {
    const float *x, *bn_gamma, *bn_beta, *W1, *a1, *B1, *W2, *a2, *B2;
    const float *Wih, *b_ih, *b_hh, *W_out, *b_out;
    float *ws, *out;
    int N;
};

__global__ __launch_bounds__(128) void kFused(KP p) {
    __shared__ __align__(16) float sm[4459];
    float* res  = sm;
    float* scsh = sm + 4032;
    float* adjL = sm + 4116;

    const int t = threadIdx.x;
    const int b = blockIdx.x;
    cg::grid_group grid = cg::this_grid();
    float* ws = p.ws;
    float* pb = ws + FPB_OFF;
    const int rowsS = p.N / FG;          // 32 at N=32768

    // ---------- phase S: per-block stats over rows [b*rowsS, +rowsS) ----------
    {
        float* fs = sm;                  // overlay [0..1260)
        float* fq = sm + 1260;           // [1260..2520)
        const int n0 = b * rowsS;
        for (int q = t; q < 315; q += 128) {
            float s0 = 0.f, s1 = 0.f, s2 = 0.f, s3 = 0.f;
            float q0 = 0.f, q1 = 0.f, q2 = 0.f, q3 = 0.f;
#pragma unroll 8
            for (int i = 0; i < rowsS; ++i) {
                const float4 a = *(const float4*)(p.x + (size_t)(n0 + i) * F1260 + q * 4);
                s0 += a.x; q0 += a.x * a.x;
                s1 += a.y; q1 += a.y * a.y;
                s2 += a.z; q2 += a.z * a.z;
                s3 += a.w; q3 += a.w * a.w;
            }
            fs[q * 4 + 0] = s0; fq[q * 4 + 0] = q0;
            fs[q * 4 + 1] = s1; fq[q * 4 + 1] = q1;
            fs[q * 4 + 2] = s2; fq[q * 4 + 2] = q2;
            fs[q * 4 + 3] = s3; fq[q * 4 + 3] = q3;
        }
        __syncthreads();
        if (t < 42) {                    // channel ch = v*6+c over f = c*210+tt*7+v
            const int v = t / 6, c = t % 6;
            float s = 0.f, q = 0.f;
#pragma unroll
            for (int tt = 0; tt < 30; ++tt) {
                const int f = c * 210 + tt * 7 + v;
                s += fs[f];
                q += fq[f];
            }
            ws[(size_t)t * FG + b] = s;          // channel-major partials
            ws[(size_t)(42 + t) * FG + b] = q;
        }
    }
    grid.sync();

    // ---------- phase R: blocks 0..83 reduce their 1024-partial row ----------
    if (b < 84) {
        const float* src = ws + (size_t)b * FG;
        float s = 0.f;
        for (int i = t; i < FG; i += 128) s += src[i];
        sm[t] = s;
        __syncthreads();
        for (int off = 64; off >= 1; off >>= 1) {
            if (t < off) sm[t] += sm[t + off];
            __syncthreads();
        }
        if (t == 0) ws[TOT_OFF + b] = sm[0];
    }
    grid.sync();

    // ---------- phase P: block 0 = old kB (BN finalize + adj + folds) ----------
    if (b == 0) {
        const int HH[6] = {0, 3, 6, 10, 13, 16};
        const int EH[6] = {0, 3, 6, 0, 3, 6};
        if (t < 42) {
            const float cnt = 30.f * (float)p.N;
            const float mean = ws[TOT_OFF + t] / cnt;
            const float var = ws[TOT_OFF + 42 + t] / cnt - mean * mean;
            const float sc = p.bn_gamma[t] * rsqrtf(var + 1e-5f);
            pb[t] = sc;
            pb[64 + t] = p.bn_beta[t] - mean * sc;
        }
        if (t >= 64 && t < 71) {
            const int idx = t - 64;
            const float* Bp = (idx < 6) ? (p.B1 + HH[idx] * 49) : p.B2;
            float* op = pb + 128 + idx * 49;
            float adj[49];
            for (int i = 0; i < 49; ++i) adj[i] = Bp[i];
            for (int i = 0; i < 7; ++i) adj[i * 8] += 1.f;
            float mn = adj[0], mx = adj[0];
            for (int i = 1; i < 49; ++i) { mn = fminf(mn, adj[i]); mx = fmaxf(mx, adj[i]); }
            const float inv = 1.f / (mx - mn);
            float rinv[7];
            for (int i = 0; i < 7; ++i) {
                float rs = 0.f;
                for (int j = 0; j < 7; ++j) { adj[i * 7 + j] = (adj[i * 7 + j] - mn) * inv; rs += adj[i * 7 + j]; }
                rinv[i] = rsqrtf(rs);
            }
            for (int i = 0; i < 7; ++i)
                for (int j = 0; j < 7; ++j)
                    op[i * 7 + j] = adj[i * 7 + j] * rinv[i] * rinv[j];
        }
        for (int task = t; task < 6 * 180; task += 128) {   // WB folds, stride 21
            const int hh = task / 180, k = task % 180;
            const int h = HH[hh];
            const float* Wp = p.W1 + ((size_t)h * 180 + k) * 9;
            float si = 0.f, sj = 0.f;
            for (int e = 0; e < 9; ++e) {
                const float w = Wp[e];
                si += w * p.a1[h * 18 + e];
                sj += w * p.a1[h * 18 + 9 + e];
            }
            pb[512 + k * 21 + hh * 3 + 0] = si;
            pb[512 + k * 21 + hh * 3 + 1] = sj;
            pb[512 + k * 21 + hh * 3 + 2] = Wp[EH[hh]];
        }
        if (t < 30) {                                       // WA2 slots
            const float* Wp = p.W2 + t * 10;
            float si = 0.f, sj = 0.f;
            for (int f = 0; f < 10; ++f) {
                const float w = Wp[f];
                si += w * p.a2[f];
                sj += w * p.a2[10 + f];
            }
            for (int c = 0; c < 6; ++c) {
                const int k = c * 30 + t;
                pb[512 + k * 21 + 18] = si;
                pb[512 + k * 21 + 19] = sj;
                pb[512 + k * 21 + 20] = Wp[0];
            }
        }
        if (t < 84) pb[4832 + t] = p.b_ih[t] + p.b_hh[t];
        for (int i = t; i < 147; i += 128) pb[4928 + i] = p.W_out[i];
        if (t < 7) pb[5078 + t] = p.b_out[t];
    }
    grid.sync();

    // ---------- phase C: r12 kC body, grid-stride 2 groups/block ----------
    const int v = (t >> 3) & 7;
    const int nl = ((t >> 6) << 3) + (t & 7);
    for (int i = t; i < 84; i += 128) scsh[i] = pb[i < 42 ? i : 22 + i];
    for (int i = t; i < 343; i += 128) adjL[i] = pb[128 + i];

    const int ngroups = p.N / 16;
    for (int g = b; g < ngroups; g += FG) {
        __syncthreads();   // res reuse across iterations + scsh/adjL visibility
        const int n0 = g * 16;

        // phase 1: dots
        if (v < 7) {
            float s1[18];
#pragma unroll
            for (int i = 0; i < 18; ++i) s1[i] = 0.f;
            const float* xb = p.x + (size_t)(n0 + nl) * F1260 + v;
            const float* WB = pb + 512;
            for (int c = 0; c < 6; ++c) {
                const float sc = scsh[v * 6 + c];
                const float sh = scsh[42 + v * 6 + c];
                const float* xr = xb + c * 210;
                const float* wb = WB + (c * 30) * 21;
                float xv[30];
#pragma unroll
                for (int tt = 0; tt < 30; ++tt) xv[tt] = xr[tt * 7];
                float g0 = 0.f, g1 = 0.f, g2 = 0.f;
#pragma unroll
                for (int tt = 0; tt < 30; ++tt) {
                    const float a = xv[tt] * sc + sh;
                    const float* w = wb + tt * 21;
#pragma unroll
                    for (int q = 0; q < 18; ++q) s1[q] += a * w[q];
                    g0 += a * w[18];
                    g1 += a * w[19];
                    g2 += a * w[20];
                }
                float* rp = res + nl * RS + 126 + (v * 6 + c) * 3;
                rp[0] = g0; rp[1] = g1; rp[2] = g2;
            }
#pragma unroll
            for (int q = 0; q < 18; ++q)
                res[nl * RS + v * 18 + q] = s1[q];
        }
        __syncthreads();

        // phase 2: GAT1 heads (pre-load all threads, then barrier -- overlay safety)
        const int hh = v;
        float si[7], sj[7], we[7];
#pragma unroll
        for (int vv = 0; vv < 7; ++vv) {
            const float* rp = res + nl * RS + vv * 18 + hh * 3;
            si[vv] = rp[0]; sj[vv] = rp[1]; we[vv] = rp[2];
        }
        __syncthreads();
        if (hh < 6) {
            float mxsj = sj[0];
#pragma unroll
            for (int j = 1; j < 7; ++j) mxsj = fmaxf(mxsj, sj[j]);
            float pr[7];
#pragma unroll
            for (int i = 0; i < 7; ++i) {
                const float m = leakyf(si[i] + mxsj);
                float den = 0.f, num = 0.f;
#pragma unroll
                for (int j = 0; j < 7; ++j) {
                    const float w = __expf(leakyf(si[i] + sj[j]) - m);
                    den += w;
                    num += w * we[j];
                }
                pr[i] = num / den;
            }
            const float* An = adjL + hh * 49;
#pragma unroll
            for (int i = 0; i < 7; ++i) {
                float r = 0.f;
#pragma unroll
                for (int k = 0; k < 7; ++k) r += An[i * 7 + k] * pr[k];
                res[nl * RS + hh * 7 + i] = eluf(r);        // xs0 [0..42)
            }
        }
        // phase 2b: GAT2 softmax-over-channels
        if (v < 7) {
            const int i = v;
            float si2[6];
#pragma unroll
            for (int c = 0; c < 6; ++c)
                si2[c] = res[nl * RS + 126 + (i * 6 + c) * 3];
            float hc[6];
#pragma unroll
            for (int c = 0; c < 6; ++c) hc[c] = 0.f;
#pragma unroll
            for (int j = 0; j < 7; ++j) {
                float s[6];
                float m = -1e30f;
#pragma unroll
                for (int c = 0; c < 6; ++c) {
                    const float* rp = res + nl * RS + 126 + (j * 6 + c) * 3;
                    s[c] = leakyf(si2[c] + rp[1]);
                    m = fmaxf(m, s[c]);
                }
                float den = 0.f;
#pragma unroll
                for (int c = 0; c < 6; ++c) { s[c] = __expf(s[c] - m); den += s[c]; }
                const float rd = 1.f / den;
#pragma unroll
                for (int c = 0; c < 6; ++c) {
                    const float wh0 = res[nl * RS + 126 + (j * 6 + c) * 3 + 2];
                    hc[c] += wh0 * s[c] * rd;
                }
            }
#pragma unroll
            for (int c = 0; c < 6; ++c)
                res[nl * RS + 84 + i * 6 + c] = hc[c];      // h2t [84..126)
        }
        __syncthreads();

        // phase 3: GAT2 adj multiply
        if (v < 6) {
            const int c = v;
            const float* An2 = adjL + 6 * 49;
            float h[7];
#pragma unroll
            for (int u = 0; u < 7; ++u) h[u] = res[nl * RS + 84 + u * 6 + c];
#pragma unroll
            for (int vv = 0; vv < 7; ++vv) {
                float r = 0.f;
#pragma unroll
                for (int u = 0; u < 7; ++u) r += h[u] * An2[u * 7 + vv];
                res[nl * RS + 42 + c * 7 + vv] = eluf(r);   // xs0 [42..84)
            }
        }
        __syncthreads();

        // phase 4: LSTM step 0
        {
            const int g8 = v;
            const float* bias = pb + 4832;
            const float4* xs4 = (const float4*)(res + nl * RS);
            for (int gi = g8; gi < 21; gi += 8) {
                float ga = bias[gi], gg = bias[42 + gi], go = bias[63 + gi];
                const float4* wa = (const float4*)(p.Wih + gi * 84);
                const float4* wg = (const float4*)(p.Wih + (42 + gi) * 84);
                const float4* wo = (const float4*)(p.Wih + (63 + gi) * 84);
#pragma unroll
                for (int k = 0; k < 21; ++k) {
                    const float4 xv = xs4[k];
                    const float4 a4 = wa[k];
                    const float4 g4 = wg[k];
                    const float4 o4 = wo[k];
                    ga += xv.x * a4.x + xv.y * a4.y + xv.z * a4.z + xv.w * a4.w;
                    gg += xv.x * g4.x + xv.y * g4.y + xv.z * g4.z + xv.w * g4.w;
                    go += xv.x * o4.x + xv.y * o4.y + xv.z * o4.z + xv.w * o4.w;
                }
                const float c1 = sigmoidf(ga) * tanh_fast(gg);
                res[nl * RS + 126 + gi] = sigmoidf(go) * tanh_fast(c1);
            }
        }
        __syncthreads();

        // phase 5: output projection
        if (t < 112) {
            const int n5 = t / 7, j = t - n5 * 7;
            const float* Wout = pb + 4928;
            float r = pb[5078 + j];
#pragma unroll
            for (int m = 0; m < 21; ++m) r += res[n5 * RS + 126 + m] * Wout[j * 21 + m];
            p.out[(size_t)n0 * 7 + t] = r;
        }
    }
}

// ================= r12 fallback path (unchanged, measured 341) =================
#define NPART 512
#define PB_OFF (NPART * 84)

__global__ __launch_bounds__(320) void kA_stats(const float* __restrict__ x,
                                                float* __restrict__ ws, int rows) {
    __shared__ float fs[1260], fq[1260];
    const int t = threadIdx.x;
    const int n0 = blockIdx.x * rows;
    if (t < 315) {
        const int f0 = t * 4;
        float s0 = 0.f, s1 = 0.f, s2 = 0.f, s3 = 0.f;
        float q0 = 0.f, q1 = 0.f, q2 = 0.f, q3 = 0.f;
#pragma unroll 16
        for (int i = 0; i < rows; ++i) {
            const float4 a = *(const float4*)(x + (size_t)(n0 + i) * F1260 + f0);
            s0 += a.x; q0 += a.x * a.x;
            s1 += a.y; q1 += a.y * a.y;
            s2 += a.z; q2 += a.z * a.z;
            s3 += a.w; q3 += a.w * a.w;
        }
        fs[f0 + 0] = s0; fq[f0 + 0] = q0;
        fs[f0 + 1] = s1; fq[f0 + 1] = q1;
        fs[f0 + 2] = s2; fq[f0 + 2] = q2;
        fs[f0 + 3] = s3; fq[f0 + 3] = q3;
    }
    __syncthreads();
    if (t < 42) {
        const int v = t / 6, c = t % 6;
        float s = 0.f, q = 0.f;
#pragma unroll
        for (int tt = 0; tt < 30; ++tt) {
            const int f = c * 210 + tt * 7 + v;
            s += fs[f];
            q += fq[f];
        }
        ws[blockIdx.x * 84 + t] = s;
        ws[blockIdx.x * 84 + 42 + t] = q;
    }
}

__global__ __launch_bounds__(384) void kB_setup(
        const float* __restrict__ bn_gamma, const float* __restrict__ bn_beta,
        const float* __restrict__ W1, const float* __restrict__ a1, const float* __restrict__ B1,
        const float* __restrict__ W2, const float* __restrict__ a2, const float* __restrict__ B2,
        const float* __restrict__ b_ih, const float* __restrict__ b_hh,
        const float* __restrict__ W_out, const float* __restrict__ b_out,
        float* __restrict__ ws, int N) {
    __shared__ float red[336];
    const int t = threadIdx.x;
    float* pb = ws + PB_OFF;
    const int HH[6] = {0, 3, 6, 10, 13, 16};
    const int EH[6] = {0, 3, 6, 0, 3, 6};

    if (t < 336) {
        const int part = t / 84, slot = t - part * 84;
        const int b0 = part * (NPART / 4);
        float s = 0.f;
#pragma unroll 8
        for (int b = 0; b < NPART / 4; ++b) s += ws[(size_t)(b0 + b) * 84 + slot];
        red[t] = s;
    }
    __syncthreads();
    if (t < 42) {
        const float s = red[t] + red[84 + t] + red[168 + t] + red[252 + t];
        const float q = red[42 + t] + red[126 + t] + red[210 + t] + red[294 + t];
        const float cnt = 30.f * (float)N;
        const float mean = s / cnt;
        const float var = q / cnt - mean * mean;
        const float sc = bn_gamma[t] * rsqrtf(var + 1e-5f);
        pb[t] = sc;
        pb[64 + t] = bn_beta[t] - mean * sc;
    }
    if (t >= 64 && t < 71) {
        const int idx = t - 64;
        const float* Bp = (idx < 6) ? (B1 + HH[idx] * 49) : B2;
        float* op = pb + 128 + idx * 49;
        float adj[49];
        for (int i = 0; i < 49; ++i) adj[i] = Bp[i];
        for (int i = 0; i < 7; ++i) adj[i * 8] += 1.f;
        float mn = adj[0], mx = adj[0];
        for (int i = 1; i < 49; ++i) { mn = fminf(mn, adj[i]); mx = fmaxf(mx, adj[i]); }
        const float inv = 1.f / (mx - mn);
        float rinv[7];
        for (int i = 0; i < 7; ++i) {
            float rs = 0.f;
            for (int j = 0; j < 7; ++j) { adj[i * 7 + j] = (adj[i * 7 + j] - mn) * inv; rs += adj[i * 7 + j]; }
            rinv[i] = rsqrtf(rs);
        }
        for (int i = 0; i < 7; ++i)
            for (int j = 0; j < 7; ++j)
                op[i * 7 + j] = adj[i * 7 + j] * rinv[i] * rinv[j];
    }
    for (int task = t; task < 6 * 180; task += 384) {
        const int hh = task / 180, k = task % 180;
        const int h = HH[hh];
        const float* Wp = W1 + ((size_t)h * 180 + k) * 9;
        float si = 0.f, sj = 0.f;
        for (int e = 0; e < 9; ++e) {
            const float w = Wp[e];
            si += w * a1[h * 18 + e];
            sj += w * a1[h * 18 + 9 + e];
        }
        pb[512 + k * 21 + hh * 3 + 0] = si;
        pb[512 + k * 21 + hh * 3 + 1] = sj;
        pb[512 + k * 21 + hh * 3 + 2] = Wp[EH[hh]];
    }
    if (t < 30) {
        const float* Wp = W2 + t * 10;
        float si = 0.f, sj = 0.f;
        for (int f = 0; f < 10; ++f) {
            const float w = Wp[f];
            si += w * a2[f];
            sj += w * a2[10 + f];
        }
        for (int c = 0; c < 6; ++c) {
            const int k = c * 30 + t;
            pb[512 + k * 21 + 18] = si;
            pb[512 + k * 21 + 19] = sj;
            pb[512 + k * 21 + 20] = Wp[0];
        }
    }
    if (t < 84) pb[4832 + t] = b_ih[t] + b_hh[t];
    if (t < 147) pb[4928 + t] = W_out[t];
    if (t < 7) pb[5078 + t] = b_out[t];
}

__global__ __launch_bounds__(128) void kC_main(const float* __restrict__ x,
        const float* __restrict__ pb, const float* __restrict__ Wih,
        float* __restrict__ outp, int N) {
    __shared__ __align__(16) float sm[4459];
    float* res  = sm;
    float* scsh = sm + 4032;
    float* adjL = sm + 4116;

    const int t = threadIdx.x;
    const int n0 = blockIdx.x * 16;
    const int v = (t >> 3) & 7;
    const int nl = ((t >> 6) << 3) + (t & 7);

    for (int i = t; i < 84; i += 128) scsh[i] = pb[i < 42 ? i : 22 + i];
    for (int i = t; i < 343; i += 128) adjL[i] = pb[128 + i];
    __syncthreads();

    if (v < 7) {
        float s1[18];
#pragma unroll
        for (int i = 0; i < 18; ++i) s1[i] = 0.f;
        const float* xb = x + (size_t)(n0 + nl) * F1260 + v;
        const float* WB = pb + 512;
        for (int c = 0; c < 6; ++c) {
            const float sc = scsh[v * 6 + c];
            const float sh = scsh[42 + v * 6 + c];
            const float* xr = xb + c * 210;
            const float* wb = WB + (c * 30) * 21;
            float xv[30];
#pragma unroll
            for (int tt = 0; tt < 30; ++tt) xv[tt] = xr[tt * 7];
            float g0 = 0.f, g1 = 0.f, g2 = 0.f;
#pragma unroll
            for (int tt = 0; tt < 30; ++tt) {
                const float a = xv[tt] * sc + sh;
                const float* w = wb + tt * 21;
#pragma unroll
                for (int q = 0; q < 18; ++q) s1[q] += a * w[q];
                g0 += a * w[18];
                g1 += a * w[19];
                g2 += a * w[20];
            }
            float* rp = res + nl * RS + 126 + (v * 6 + c) * 3;
            rp[0] = g0; rp[1] = g1; rp[2] = g2;
        }
#pragma unroll
        for (int q = 0; q < 18; ++q)
            res[nl * RS + v * 18 + q] = s1[q];
    }
    __syncthreads();

    const int hh = v;
    float si[7], sj[7], we[7];
#pragma unroll
    for (int vv = 0; vv < 7; ++vv) {
        const float* rp = res + nl * RS + vv * 18 + hh * 3;
        si[vv] = rp[0]; sj[vv] = rp[1]; we[vv] = rp[2];
    }
    __syncthreads();
    if (hh < 6) {
        float mxsj = sj[0];
#pragma unroll
        for (int j = 1; j < 7; ++j) mxsj = fmaxf(mxsj, sj[j]);
        float pr[7];
#pragma unroll
        for (int i = 0; i < 7; ++i) {
            const float m = leakyf(si[i] + mxsj);
            float den = 0.f, num = 0.f;
#pragma unroll
            for (int j = 0; j < 7; ++j) {
                const float w = __expf(leakyf(si[i] + sj[j]) - m);
                den += w;
                num += w * we[j];
            }
            pr[i] = num / den;
        }
        const float* An = adjL + hh * 49;
#pragma unroll
        for (int i = 0; i < 7; ++i) {
            float r = 0.f;
#pragma unroll
            for (int k = 0; k < 7; ++k) r += An[i * 7 + k] * pr[k];
            res[nl * RS + hh * 7 + i] = eluf(r);
        }
    }
    if (v < 7) {
        const int i = v;
        float si2[6];
#pragma unroll
        for (int c = 0; c < 6; ++c)
            si2[c] = res[nl * RS + 126 + (i * 6 + c) * 3];
        float hc[6];
#pragma unroll
        for (int c = 0; c < 6; ++c) hc[c] = 0.f;
#pragma unroll
        for (int j = 0; j < 7; ++j) {
            float s[6];
            float m = -1e30f;
#pragma unroll
            for (int c = 0; c < 6; ++c) {
                const float* rp = res + nl * RS + 126 + (j * 6 + c) * 3;
                s[c] = leakyf(si2[c] + rp[1]);
                m = fmaxf(m, s[c]);
            }
            float den = 0.f;
#pragma unroll
            for (int c = 0; c < 6; ++c) { s[c] = __expf(s[c] - m); den += s[c]; }
            const float rd = 1.f / den;
#pragma unroll
            for (int c = 0; c < 6; ++c) {
                const float wh0 = res[nl * RS + 126 + (j * 6 + c) * 3 + 2];
                hc[c] += wh0 * s[c] * rd;
            }
        }
#pragma unroll
        for (int c = 0; c < 6; ++c)
            res[nl * RS + 84 + i * 6 + c] = hc[c];
    }
    __syncthreads();

    if (v < 6) {
        const int c = v;
        const float* An2 = adjL + 6 * 49;
        float h[7];
#pragma unroll
        for (int u = 0; u < 7; ++u) h[u] = res[nl * RS + 84 + u * 6 + c];
#pragma unroll
        for (int vv = 0; vv < 7; ++vv) {
            float r = 0.f;
#pragma unroll
            for (int u = 0; u < 7; ++u) r += h[u] * An2[u * 7 + vv];
            res[nl * RS + 42 + c * 7 + vv] = eluf(r);
        }
    }
    __syncthreads();

    {
        const int g8 = v;
        const float* bias = pb + 4832;
        const float4* xs4 = (const float4*)(res + nl * RS);
        for (int gi = g8; gi < 21; gi += 8) {
            float ga = bias[gi], gg = bias[42 + gi], go = bias[63 + gi];
            const float4* wa = (const float4*)(Wih + gi * 84);
            const float4* wg = (const float4*)(Wih + (42 + gi) * 84);
            const float4* wo = (const float4*)(Wih + (63 + gi) * 84);
#pragma unroll
            for (int k = 0; k < 21; ++k) {
                const float4 xv = xs4[k];
                const float4 a4 = wa[k];
                const float4 g4 = wg[k];
                const float4 o4 = wo[k];
                ga += xv.x * a4.x + xv.y * a4.y + xv.z * a4.z + xv.w * a4.w;
                gg += xv.x * g4.x + xv.y * g4.y + xv.z * g4.z + xv.w * g4.w;
                go += xv.x * o4.x + xv.y * o4.y + xv.z * o4.z + xv.w * o4.w;
            }
            const float c1 = sigmoidf(ga) * tanh_fast(gg);
            res[nl * RS + 126 + gi] = sigmoidf(go) * tanh_fast(c1);
        }
    }
    __syncthreads();

    if (t < 112) {
        const int n5 = t / 7, j = t - n5 * 7;
        const float* Wout = pb + 4928;
        float r = pb[5078 + j];
#pragma unroll
        for (int m = 0; m < 21; ++m) r += res[n5 * RS + 126 + m] * Wout[j * 21 + m];
        outp[(size_t)n0 * 7 + t] = r;
    }
}

extern "C" void kernel_launch(void* const* d_in, const int* in_sizes, int n_in,
                              void* d_out, int out_size, void* d_ws, size_t ws_size,
                              hipStream_t stream) {
    const int N = in_sizes[0] / F1260;

    const float* x        = (const float*)d_in[0];
    const float* bn_gamma = (const float*)d_in[1];
    const float* bn_beta  = (const float*)d_in[2];
    const float* W1       = (const float*)d_in[3];
    const float* a1       = (const float*)d_in[4];
    const float* B1       = (const float*)d_in[5];
    const float* W2       = (const float*)d_in[6];
    const float* a2       = (const float*)d_in[7];
    const float* B2       = (const float*)d_in[8];
    const float* W_ih     = (const float*)d_in[9];
    // d_in[10] = W_hh unused (h0 = 0 -> only LSTM step 0 matters)
    const float* b_ih     = (const float*)d_in[11];
    const float* b_hh     = (const float*)d_in[12];
    const float* W_out    = (const float*)d_in[13];
    const float* b_out    = (const float*)d_in[14];

    float* wsf = (float*)d_ws;

    hipError_t e = hipErrorUnknown;
    const bool okFused = (N % FG == 0) && (N % 16 == 0) &&
                         (ws_size >= (size_t)(FPB_OFF + 5085 + 64) * sizeof(float));
    if (okFused) {
        KP p = { x, bn_gamma, bn_beta, W1, a1, B1, W2, a2, B2,
                 W_ih, b_ih, b_hh, W_out, b_out, wsf, (float*)d_out, N };
        void* args[] = { &p };
        e = hipLaunchCooperativeKernel((void*)kFused, dim3(FG), dim3(128),
                                       args, 0, stream);
    }
    if (e != hipSuccess) {
        (void)hipGetLastError();          // clear sticky error, use r12 path
        kA_stats<<<dim3(NPART), dim3(320), 0, stream>>>(x, wsf, N / NPART);
        kB_setup<<<dim3(1), dim3(384), 0, stream>>>(bn_gamma, bn_beta, W1, a1, B1,
                                                    W2, a2, B2, b_ih, b_hh,
                                                    W_out, b_out, wsf, N);
        kC_main<<<dim3(N / 16), dim3(128), 0, stream>>>(x, wsf + PB_OFF, W_ih,
                                                        (float*)d_out, N);
    }
}

// Round 14
// 708.621 us; speedup vs baseline: 1.1442x; 1.1442x over previous
//
#include <hip/hip_runtime.h>
#include <hip/hip_cooperative_groups.h>

namespace cg = cooperative_groups;

#define F1260 1260

__device__ __forceinline__ float leakyf(float x) { return x >= 0.f ? x : 0.2f * x; }
__device__ __forceinline__ float eluf(float x) { return x > 0.f ? x : expm1f(x); }
__device__ __forceinline__ float sigmoidf(float x) { return 1.f / (1.f + __expf(-x)); }
// fast tanh: exact saturation, ~1e-6 abs err
__device__ __forceinline__ float tanh_fast(float x) { return 1.f - 2.f / (__expf(2.f * x) + 1.f); }

// ================= fused cooperative path =================
// r13 post-mortem: struct-passed non-restrict pointers demoted the wave-uniform
// weight stream from s_load to per-lane vector loads (VALUBusy 37->7.8%,
// VGPR 56->92, 595 us). This version removes all alias-analysis reliance:
// individual __restrict__ params + ALL phase-C tables staged to LDS (WB at
// stride 24 -> 16B rows -> ds_read_b128 broadcast). FETCH=170 MB (x once)
// was verified in r13 -- that part of the fusion works.
// Grid 1024 x 128 thr; LDS 36068 B -> exactly 4 blocks/CU (co-residency ok).
// ws: partials [84][1024] @0; totals[84] @86016; pb @86272
//     (pb: 0 scale,64 shift,128 adj; 512 WB stride-24 (4320); 4832 bias,
//      4928 Wout, 5078 bout)
#define FG 1024
#define TOT_OFF 86016
#define FPB_OFF 86272
#define RS 252
// LDS float offsets
#define L_WB   4032     // 180*24 = 4320
#define L_SC   8352     // 84
#define L_ADJ  8436     // 343
#define L_BIAS 8779     // 84
#define L_WOUT 8863     // 147
#define L_BOUT 9010     // 7
#define L_TOT  9017     // floats = 36068 B

__global__ __launch_bounds__(128) void kFused(
        const float* __restrict__ x, const float* __restrict__ bn_gamma,
        const float* __restrict__ bn_beta, const float* __restrict__ W1,
        const float* __restrict__ a1, const float* __restrict__ B1,
        const float* __restrict__ W2, const float* __restrict__ a2,
        const float* __restrict__ B2, const float* __restrict__ Wih,
        const float* __restrict__ b_ih, const float* __restrict__ b_hh,
        const float* __restrict__ W_out, const float* __restrict__ b_out,
        float* __restrict__ ws, float* __restrict__ outp, int N) {
    __shared__ __align__(16) float sm[L_TOT];
    float* res = sm;

    const int t = threadIdx.x;
    const int b = blockIdx.x;
    cg::grid_group grid = cg::this_grid();
    float* pb = ws + FPB_OFF;
    const int rowsS = N / FG;

    // ---------- phase S: per-block channel stats (x read once, L3-warms) ----------
    {
        float* fs = sm;                  // overlay [0..1260)
        float* fq = sm + 1260;           // [1260..2520)
        const int n0 = b * rowsS;
        for (int q = t; q < 315; q += 128) {
            float s0 = 0.f, s1 = 0.f, s2 = 0.f, s3 = 0.f;
            float q0 = 0.f, q1 = 0.f, q2 = 0.f, q3 = 0.f;
#pragma unroll 8
            for (int i = 0; i < rowsS; ++i) {
                const float4 a = *(const float4*)(x + (size_t)(n0 + i) * F1260 + q * 4);
                s0 += a.x; q0 += a.x * a.x;
                s1 += a.y; q1 += a.y * a.y;
                s2 += a.z; q2 += a.z * a.z;
                s3 += a.w; q3 += a.w * a.w;
            }
            fs[q * 4 + 0] = s0; fq[q * 4 + 0] = q0;
            fs[q * 4 + 1] = s1; fq[q * 4 + 1] = q1;
            fs[q * 4 + 2] = s2; fq[q * 4 + 2] = q2;
            fs[q * 4 + 3] = s3; fq[q * 4 + 3] = q3;
        }
        __syncthreads();
        if (t < 42) {                    // channel ch = v*6+c over f = c*210+tt*7+v
            const int v = t / 6, c = t % 6;
            float s = 0.f, q = 0.f;
#pragma unroll
            for (int tt = 0; tt < 30; ++tt) {
                const int f = c * 210 + tt * 7 + v;
                s += fs[f];
                q += fq[f];
            }
            ws[(size_t)t * FG + b] = s;          // channel-major partials
            ws[(size_t)(42 + t) * FG + b] = q;
        }
    }
    grid.sync();

    // ---------- phase R: blocks 0..83 reduce their 1024-partial row ----------
    if (b < 84) {
        const float* src = ws + (size_t)b * FG;
        float s = 0.f;
        for (int i = t; i < FG; i += 128) s += src[i];
        __syncthreads();                 // fs/fq reuse barrier
        sm[t] = s;
        __syncthreads();
        for (int off = 64; off >= 1; off >>= 1) {
            if (t < off) sm[t] += sm[t + off];
            __syncthreads();
        }
        if (t == 0) ws[TOT_OFF + b] = sm[0];
    }
    grid.sync();

    // ---------- phase P: block 0 finalizes BN + adj + folds (WB stride 24) ----------
    if (b == 0) {
        const int HH[6] = {0, 3, 6, 10, 13, 16};
        const int EH[6] = {0, 3, 6, 0, 3, 6};
        if (t < 42) {
            const float cnt = 30.f * (float)N;
            const float mean = ws[TOT_OFF + t] / cnt;
            const float var = ws[TOT_OFF + 42 + t] / cnt - mean * mean;
            const float sc = bn_gamma[t] * rsqrtf(var + 1e-5f);
            pb[t] = sc;
            pb[64 + t] = bn_beta[t] - mean * sc;
        }
        if (t >= 64 && t < 71) {
            const int idx = t - 64;
            const float* Bp = (idx < 6) ? (B1 + HH[idx] * 49) : B2;
            float* op = pb + 128 + idx * 49;
            float adj[49];
            for (int i = 0; i < 49; ++i) adj[i] = Bp[i];
            for (int i = 0; i < 7; ++i) adj[i * 8] += 1.f;
            float mn = adj[0], mx = adj[0];
            for (int i = 1; i < 49; ++i) { mn = fminf(mn, adj[i]); mx = fmaxf(mx, adj[i]); }
            const float inv = 1.f / (mx - mn);
            float rinv[7];
            for (int i = 0; i < 7; ++i) {
                float rs = 0.f;
                for (int j = 0; j < 7; ++j) { adj[i * 7 + j] = (adj[i * 7 + j] - mn) * inv; rs += adj[i * 7 + j]; }
                rinv[i] = rsqrtf(rs);
            }
            for (int i = 0; i < 7; ++i)
                for (int j = 0; j < 7; ++j)
                    op[i * 7 + j] = adj[i * 7 + j] * rinv[i] * rinv[j];
        }
        for (int task = t; task < 6 * 180; task += 128) {   // WB folds, stride 24
            const int hh = task / 180, k = task % 180;
            const int h = HH[hh];
            const float* Wp = W1 + ((size_t)h * 180 + k) * 9;
            float si = 0.f, sj = 0.f;
            for (int e = 0; e < 9; ++e) {
                const float w = Wp[e];
                si += w * a1[h * 18 + e];
                sj += w * a1[h * 18 + 9 + e];
            }
            pb[512 + k * 24 + hh * 3 + 0] = si;
            pb[512 + k * 24 + hh * 3 + 1] = sj;
            pb[512 + k * 24 + hh * 3 + 2] = Wp[EH[hh]];
        }
        if (t < 30) {                                       // WA2 slots
            const float* Wp = W2 + t * 10;
            float si = 0.f, sj = 0.f;
            for (int f = 0; f < 10; ++f) {
                const float w = Wp[f];
                si += w * a2[f];
                sj += w * a2[10 + f];
            }
            for (int c = 0; c < 6; ++c) {
                const int k = c * 30 + t;
                pb[512 + k * 24 + 18] = si;
                pb[512 + k * 24 + 19] = sj;
                pb[512 + k * 24 + 20] = Wp[0];
            }
        }
        if (t < 84) pb[4832 + t] = b_ih[t] + b_hh[t];
        for (int i = t; i < 147; i += 128) pb[4928 + i] = W_out[i];
        if (t < 7) pb[5078 + t] = b_out[t];
    }
    grid.sync();

    // ---------- stage ALL phase-C tables to LDS (once per block) ----------
    for (int i = t; i < 4320; i += 128) sm[L_WB + i] = pb[512 + i];
    for (int i = t; i < 84; i += 128)  sm[L_SC + i] = pb[i < 42 ? i : 22 + i];
    for (int i = t; i < 343; i += 128) sm[L_ADJ + i] = pb[128 + i];
    for (int i = t; i < 84; i += 128)  sm[L_BIAS + i] = pb[4832 + i];
    for (int i = t; i < 147; i += 128) sm[L_WOUT + i] = pb[4928 + i];
    if (t < 7) sm[L_BOUT + t] = pb[5078 + t];

    const float* WBl  = sm + L_WB;
    const float* scsh = sm + L_SC;
    const float* adjL = sm + L_ADJ;
    const float* bias = sm + L_BIAS;
    const float* Wout = sm + L_WOUT;

    // ---------- phase C: r12 kC body, grid-stride 2 groups/block ----------
    const int v = (t >> 3) & 7;
    const int nl = ((t >> 6) << 3) + (t & 7);
    const int ngroups = N / 16;
    for (int g = b; g < ngroups; g += FG) {
        __syncthreads();   // staging visibility + res reuse across iterations
        const int n0 = g * 16;

        // phase 1: dots (x gather per-lane; weights = LDS broadcast b128)
        if (v < 7) {
            float s1[18];
#pragma unroll
            for (int i = 0; i < 18; ++i) s1[i] = 0.f;
            const float* xb = x + (size_t)(n0 + nl) * F1260 + v;
            for (int c = 0; c < 6; ++c) {
                const float sc = scsh[v * 6 + c];
                const float sh = scsh[42 + v * 6 + c];
                const float* xr = xb + c * 210;
                const float* wb = WBl + (c * 30) * 24;
                float xv[30];
#pragma unroll
                for (int tt = 0; tt < 30; ++tt) xv[tt] = xr[tt * 7];
                float g0 = 0.f, g1 = 0.f, g2 = 0.f;
#pragma unroll
                for (int tt = 0; tt < 30; ++tt) {
                    const float a = xv[tt] * sc + sh;
                    const float* w = wb + tt * 24;
#pragma unroll
                    for (int q = 0; q < 18; ++q) s1[q] += a * w[q];
                    g0 += a * w[18];
                    g1 += a * w[19];
                    g2 += a * w[20];
                }
                float* rp = res + nl * RS + 126 + (v * 6 + c) * 3;
                rp[0] = g0; rp[1] = g1; rp[2] = g2;
            }
#pragma unroll
            for (int q = 0; q < 18; ++q)
                res[nl * RS + v * 18 + q] = s1[q];
        }
        __syncthreads();

        // phase 2: GAT1 heads (pre-load all threads, then barrier -- overlay safety)
        const int hh = v;
        float si[7], sj[7], we[7];
#pragma unroll
        for (int vv = 0; vv < 7; ++vv) {
            const float* rp = res + nl * RS + vv * 18 + hh * 3;
            si[vv] = rp[0]; sj[vv] = rp[1]; we[vv] = rp[2];
        }
        __syncthreads();
        if (hh < 6) {
            float mxsj = sj[0];
#pragma unroll
            for (int j = 1; j < 7; ++j) mxsj = fmaxf(mxsj, sj[j]);
            float pr[7];
#pragma unroll
            for (int i = 0; i < 7; ++i) {
                const float m = leakyf(si[i] + mxsj);
                float den = 0.f, num = 0.f;
#pragma unroll
                for (int j = 0; j < 7; ++j) {
                    const float w = __expf(leakyf(si[i] + sj[j]) - m);
                    den += w;
                    num += w * we[j];
                }
                pr[i] = num / den;
            }
            const float* An = adjL + hh * 49;
#pragma unroll
            for (int i = 0; i < 7; ++i) {
                float r = 0.f;
#pragma unroll
                for (int k = 0; k < 7; ++k) r += An[i * 7 + k] * pr[k];
                res[nl * RS + hh * 7 + i] = eluf(r);        // xs0 [0..42)
            }
        }
        // phase 2b: GAT2 softmax-over-channels
        if (v < 7) {
            const int i = v;
            float si2[6];
#pragma unroll
            for (int c = 0; c < 6; ++c)
                si2[c] = res[nl * RS + 126 + (i * 6 + c) * 3];
            float hc[6];
#pragma unroll
            for (int c = 0; c < 6; ++c) hc[c] = 0.f;
#pragma unroll
            for (int j = 0; j < 7; ++j) {
                float s[6];
                float m = -1e30f;
#pragma unroll
                for (int c = 0; c < 6; ++c) {
                    const float* rp = res + nl * RS + 126 + (j * 6 + c) * 3;
                    s[c] = leakyf(si2[c] + rp[1]);
                    m = fmaxf(m, s[c]);
                }
                float den = 0.f;
#pragma unroll
                for (int c = 0; c < 6; ++c) { s[c] = __expf(s[c] - m); den += s[c]; }
                const float rd = 1.f / den;
#pragma unroll
                for (int c = 0; c < 6; ++c) {
                    const float wh0 = res[nl * RS + 126 + (j * 6 + c) * 3 + 2];
                    hc[c] += wh0 * s[c] * rd;
                }
            }
#pragma unroll
            for (int c = 0; c < 6; ++c)
                res[nl * RS + 84 + i * 6 + c] = hc[c];      // h2t [84..126)
        }
        __syncthreads();

        // phase 3: GAT2 adj multiply
        if (v < 6) {
            const int c = v;
            const float* An2 = adjL + 6 * 49;
            float h[7];
#pragma unroll
            for (int u = 0; u < 7; ++u) h[u] = res[nl * RS + 84 + u * 6 + c];
#pragma unroll
            for (int vv = 0; vv < 7; ++vv) {
                float r = 0.f;
#pragma unroll
                for (int u = 0; u < 7; ++u) r += h[u] * An2[u * 7 + vv];
                res[nl * RS + 42 + c * 7 + vv] = eluf(r);   // xs0 [42..84)
            }
        }
        __syncthreads();

        // phase 4: LSTM step 0 (Wih = const restrict global -> scalar stream)
        {
            const int g8 = v;
            const float4* xs4 = (const float4*)(res + nl * RS);
            for (int gi = g8; gi < 21; gi += 8) {
                float ga = bias[gi], gg = bias[42 + gi], go = bias[63 + gi];
                const float4* wa = (const float4*)(Wih + gi * 84);
                const float4* wg = (const float4*)(Wih + (42 + gi) * 84);
                const float4* wo = (const float4*)(Wih + (63 + gi) * 84);
#pragma unroll
                for (int k = 0; k < 21; ++k) {
                    const float4 xv = xs4[k];
                    const float4 a4 = wa[k];
                    const float4 g4 = wg[k];
                    const float4 o4 = wo[k];
                    ga += xv.x * a4.x + xv.y * a4.y + xv.z * a4.z + xv.w * a4.w;
                    gg += xv.x * g4.x + xv.y * g4.y + xv.z * g4.z + xv.w * g4.w;
                    go += xv.x * o4.x + xv.y * o4.y + xv.z * o4.z + xv.w * o4.w;
                }
                const float c1 = sigmoidf(ga) * tanh_fast(gg);
                res[nl * RS + 126 + gi] = sigmoidf(go) * tanh_fast(c1);
            }
        }
        __syncthreads();

        // phase 5: output projection
        if (t < 112) {
            const int n5 = t / 7, j = t - n5 * 7;
            float r = sm[L_BOUT + j];
#pragma unroll
            for (int m = 0; m < 21; ++m) r += res[n5 * RS + 126 + m] * Wout[j * 21 + m];
            outp[(size_t)n0 * 7 + t] = r;
        }
    }
}

// ================= r12 fallback path (unchanged, measured 341) =================
#define NPART 512
#define PB_OFF (NPART * 84)

__global__ __launch_bounds__(320) void kA_stats(const float* __restrict__ x,
                                                float* __restrict__ ws, int rows) {
    __shared__ float fs[1260], fq[1260];
    const int t = threadIdx.x;
    const int n0 = blockIdx.x * rows;
    if (t < 315) {
        const int f0 = t * 4;
        float s0 = 0.f, s1 = 0.f, s2 = 0.f, s3 = 0.f;
        float q0 = 0.f, q1 = 0.f, q2 = 0.f, q3 = 0.f;
#pragma unroll 16
        for (int i = 0; i < rows; ++i) {
            const float4 a = *(const float4*)(x + (size_t)(n0 + i) * F1260 + f0);
            s0 += a.x; q0 += a.x * a.x;
            s1 += a.y; q1 += a.y * a.y;
            s2 += a.z; q2 += a.z * a.z;
            s3 += a.w; q3 += a.w * a.w;
        }
        fs[f0 + 0] = s0; fq[f0 + 0] = q0;
        fs[f0 + 1] = s1; fq[f0 + 1] = q1;
        fs[f0 + 2] = s2; fq[f0 + 2] = q2;
        fs[f0 + 3] = s3; fq[f0 + 3] = q3;
    }
    __syncthreads();
    if (t < 42) {
        const int v = t / 6, c = t % 6;
        float s = 0.f, q = 0.f;
#pragma unroll
        for (int tt = 0; tt < 30; ++tt) {
            const int f = c * 210 + tt * 7 + v;
            s += fs[f];
            q += fq[f];
        }
        ws[blockIdx.x * 84 + t] = s;
        ws[blockIdx.x * 84 + 42 + t] = q;
    }
}

__global__ __launch_bounds__(384) void kB_setup(
        const float* __restrict__ bn_gamma, const float* __restrict__ bn_beta,
        const float* __restrict__ W1, const float* __restrict__ a1, const float* __restrict__ B1,
        const float* __restrict__ W2, const float* __restrict__ a2, const float* __restrict__ B2,
        const float* __restrict__ b_ih, const float* __restrict__ b_hh,
        const float* __restrict__ W_out, const float* __restrict__ b_out,
        float* __restrict__ ws, int N) {
    __shared__ float red[336];
    const int t = threadIdx.x;
    float* pb = ws + PB_OFF;
    const int HH[6] = {0, 3, 6, 10, 13, 16};
    const int EH[6] = {0, 3, 6, 0, 3, 6};

    if (t < 336) {
        const int part = t / 84, slot = t - part * 84;
        const int b0 = part * (NPART / 4);
        float s = 0.f;
#pragma unroll 8
        for (int b = 0; b < NPART / 4; ++b) s += ws[(size_t)(b0 + b) * 84 + slot];
        red[t] = s;
    }
    __syncthreads();
    if (t < 42) {
        const float s = red[t] + red[84 + t] + red[168 + t] + red[252 + t];
        const float q = red[42 + t] + red[126 + t] + red[210 + t] + red[294 + t];
        const float cnt = 30.f * (float)N;
        const float mean = s / cnt;
        const float var = q / cnt - mean * mean;
        const float sc = bn_gamma[t] * rsqrtf(var + 1e-5f);
        pb[t] = sc;
        pb[64 + t] = bn_beta[t] - mean * sc;
    }
    if (t >= 64 && t < 71) {
        const int idx = t - 64;
        const float* Bp = (idx < 6) ? (B1 + HH[idx] * 49) : B2;
        float* op = pb + 128 + idx * 49;
        float adj[49];
        for (int i = 0; i < 49; ++i) adj[i] = Bp[i];
        for (int i = 0; i < 7; ++i) adj[i * 8] += 1.f;
        float mn = adj[0], mx = adj[0];
        for (int i = 1; i < 49; ++i) { mn = fminf(mn, adj[i]); mx = fmaxf(mx, adj[i]); }
        const float inv = 1.f / (mx - mn);
        float rinv[7];
        for (int i = 0; i < 7; ++i) {
            float rs = 0.f;
            for (int j = 0; j < 7; ++j) { adj[i * 7 + j] = (adj[i * 7 + j] - mn) * inv; rs += adj[i * 7 + j]; }
            rinv[i] = rsqrtf(rs);
        }
        for (int i = 0; i < 7; ++i)
            for (int j = 0; j < 7; ++j)
                op[i * 7 + j] = adj[i * 7 + j] * rinv[i] * rinv[j];
    }
    for (int task = t; task < 6 * 180; task += 384) {
        const int hh = task / 180, k = task % 180;
        const int h = HH[hh];
        const float* Wp = W1 + ((size_t)h * 180 + k) * 9;
        float si = 0.f, sj = 0.f;
        for (int e = 0; e < 9; ++e) {
            const float w = Wp[e];
            si += w * a1[h * 18 + e];
            sj += w * a1[h * 18 + 9 + e];
        }
        pb[512 + k * 21 + hh * 3 + 0] = si;
        pb[512 + k * 21 + hh * 3 + 1] = sj;
        pb[512 + k * 21 + hh * 3 + 2] = Wp[EH[hh]];
    }
    if (t < 30) {
        const float* Wp = W2 + t * 10;
        float si = 0.f, sj = 0.f;
        for (int f = 0; f < 10; ++f) {
            const float w = Wp[f];
            si += w * a2[f];
            sj += w * a2[10 + f];
        }
        for (int c = 0; c < 6; ++c) {
            const int k = c * 30 + t;
            pb[512 + k * 21 + 18] = si;
            pb[512 + k * 21 + 19] = sj;
            pb[512 + k * 21 + 20] = Wp[0];
        }
    }
    if (t < 84) pb[4832 + t] = b_ih[t] + b_hh[t];
    if (t < 147) pb[4928 + t] = W_out[t];
    if (t < 7) pb[5078 + t] = b_out[t];
}

__global__ __launch_bounds__(128) void kC_main(const float* __restrict__ x,
        const float* __restrict__ pb, const float* __restrict__ Wih,
        float* __restrict__ outp, int N) {
    __shared__ __align__(16) float sm[4459];
    float* res  = sm;
    float* scsh = sm + 4032;
    float* adjL = sm + 4116;

    const int t = threadIdx.x;
    const int n0 = blockIdx.x * 16;
    const int v = (t >> 3) & 7;
    const int nl = ((t >> 6) << 3) + (t & 7);

    for (int i = t; i < 84; i += 128) scsh[i] = pb[i < 42 ? i : 22 + i];
    for (int i = t; i < 343; i += 128) adjL[i] = pb[128 + i];
    __syncthreads();

    if (v < 7) {
        float s1[18];
#pragma unroll
        for (int i = 0; i < 18; ++i) s1[i] = 0.f;
        const float* xb = x + (size_t)(n0 + nl) * F1260 + v;
        const float* WB = pb + 512;
        for (int c = 0; c < 6; ++c) {
            const float sc = scsh[v * 6 + c];
            const float sh = scsh[42 + v * 6 + c];
            const float* xr = xb + c * 210;
            const float* wb = WB + (c * 30) * 21;
            float xv[30];
#pragma unroll
            for (int tt = 0; tt < 30; ++tt) xv[tt] = xr[tt * 7];
            float g0 = 0.f, g1 = 0.f, g2 = 0.f;
#pragma unroll
            for (int tt = 0; tt < 30; ++tt) {
                const float a = xv[tt] * sc + sh;
                const float* w = wb + tt * 21;
#pragma unroll
                for (int q = 0; q < 18; ++q) s1[q] += a * w[q];
                g0 += a * w[18];
                g1 += a * w[19];
                g2 += a * w[20];
            }
            float* rp = res + nl * RS + 126 + (v * 6 + c) * 3;
            rp[0] = g0; rp[1] = g1; rp[2] = g2;
        }
#pragma unroll
        for (int q = 0; q < 18; ++q)
            res[nl * RS + v * 18 + q] = s1[q];
    }
    __syncthreads();

    const int hh = v;
    float si[7], sj[7], we[7];
#pragma unroll
    for (int vv = 0; vv < 7; ++vv) {
        const float* rp = res + nl * RS + vv * 18 + hh * 3;
        si[vv] = rp[0]; sj[vv] = rp[1]; we[vv] = rp[2];
    }
    __syncthreads();
    if (hh < 6) {
        float mxsj = sj[0];
#pragma unroll
        for (int j = 1; j < 7; ++j) mxsj = fmaxf(mxsj, sj[j]);
        float pr[7];
#pragma unroll
        for (int i = 0; i < 7; ++i) {
            const float m = leakyf(si[i] + mxsj);
            float den = 0.f, num = 0.f;
#pragma unroll
            for (int j = 0; j < 7; ++j) {
                const float w = __expf(leakyf(si[i] + sj[j]) - m);
                den += w;
                num += w * we[j];
            }
            pr[i] = num / den;
        }
        const float* An = adjL + hh * 49;
#pragma unroll
        for (int i = 0; i < 7; ++i) {
            float r = 0.f;
#pragma unroll
            for (int k = 0; k < 7; ++k) r += An[i * 7 + k] * pr[k];
            res[nl * RS + hh * 7 + i] = eluf(r);
        }
    }
    if (v < 7) {
        const int i = v;
        float si2[6];
#pragma unroll
        for (int c = 0; c < 6; ++c)
            si2[c] = res[nl * RS + 126 + (i * 6 + c) * 3];
        float hc[6];
#pragma unroll
        for (int c = 0; c < 6; ++c) hc[c] = 0.f;
#pragma unroll
        for (int j = 0; j < 7; ++j) {
            float s[6];
            float m = -1e30f;
#pragma unroll
            for (int c = 0; c < 6; ++c) {
                const float* rp = res + nl * RS + 126 + (j * 6 + c) * 3;
                s[c] = leakyf(si2[c] + rp[1]);
                m = fmaxf(m, s[c]);
            }
            float den = 0.f;
#pragma unroll
            for (int c = 0; c < 6; ++c) { s[c] = __expf(s[c] - m); den += s[c]; }
            const float rd = 1.f / den;
#pragma unroll
            for (int c = 0; c < 6; ++c) {
                const float wh0 = res[nl * RS + 126 + (j * 6 + c) * 3 + 2];
                hc[c] += wh0 * s[c] * rd;
            }
        }
#pragma unroll
        for (int c = 0; c < 6; ++c)
            res[nl * RS + 84 + i * 6 + c] = hc[c];
    }
    __syncthreads();

    if (v < 6) {
        const int c = v;
        const float* An2 = adjL + 6 * 49;
        float h[7];
#pragma unroll
        for (int u = 0; u < 7; ++u) h[u] = res[nl * RS + 84 + u * 6 + c];
#pragma unroll
        for (int vv = 0; vv < 7; ++vv) {
            float r = 0.f;
#pragma unroll
            for (int u = 0; u < 7; ++u) r += h[u] * An2[u * 7 + vv];
            res[nl * RS + 42 + c * 7 + vv] = eluf(r);
        }
    }
    __syncthreads();

    {
        const int g8 = v;
        const float* bias = pb + 4832;
        const float4* xs4 = (const float4*)(res + nl * RS);
        for (int gi = g8; gi < 21; gi += 8) {
            float ga = bias[gi], gg = bias[42 + gi], go = bias[63 + gi];
            const float4* wa = (const float4*)(Wih + gi * 84);
            const float4* wg = (const float4*)(Wih + (42 + gi) * 84);
            const float4* wo = (const float4*)(Wih + (63 + gi) * 84);
#pragma unroll
            for (int k = 0; k < 21; ++k) {
                const float4 xv = xs4[k];
                const float4 a4 = wa[k];
                const float4 g4 = wg[k];
                const float4 o4 = wo[k];
                ga += xv.x * a4.x + xv.y * a4.y + xv.z * a4.z + xv.w * a4.w;
                gg += xv.x * g4.x + xv.y * g4.y + xv.z * g4.z + xv.w * g4.w;
                go += xv.x * o4.x + xv.y * o4.y + xv.z * o4.z + xv.w * o4.w;
            }
            const float c1 = sigmoidf(ga) * tanh_fast(gg);
            res[nl * RS + 126 + gi] = sigmoidf(go) * tanh_fast(c1);
        }
    }
    __syncthreads();

    if (t < 112) {
        const int n5 = t / 7, j = t - n5 * 7;
        const float* Wout = pb + 4928;
        float r = pb[5078 + j];
#pragma unroll
        for (int m = 0; m < 21; ++m) r += res[n5 * RS + 126 + m] * Wout[j * 21 + m];
        outp[(size_t)n0 * 7 + t] = r;
    }
}

extern "C" void kernel_launch(void* const* d_in, const int* in_sizes, int n_in,
                              void* d_out, int out_size, void* d_ws, size_t ws_size,
                              hipStream_t stream) {
    const int N = in_sizes[0] / F1260;

    const float* x        = (const float*)d_in[0];
    const float* bn_gamma = (const float*)d_in[1];
    const float* bn_beta  = (const float*)d_in[2];
    const float* W1       = (const float*)d_in[3];
    const float* a1       = (const float*)d_in[4];
    const float* B1       = (const float*)d_in[5];
    const float* W2       = (const float*)d_in[6];
    const float* a2       = (const float*)d_in[7];
    const float* B2       = (const float*)d_in[8];
    const float* W_ih     = (const float*)d_in[9];
    // d_in[10] = W_hh unused (h0 = 0 -> only LSTM step 0 matters)
    const float* b_ih     = (const float*)d_in[11];
    const float* b_hh     = (const float*)d_in[12];
    const float* W_out    = (const float*)d_in[13];
    const float* b_out    = (const float*)d_in[14];

    float* wsf = (float*)d_ws;
    float* outp = (float*)d_out;

    hipError_t e = hipErrorUnknown;
    const bool okFused = (N % FG == 0) && (N % 16 == 0) &&
                         (ws_size >= (size_t)(FPB_OFF + 5085 + 64) * sizeof(float));
    if (okFused) {
        int Nv = N;
        void* args[] = { &x, &bn_gamma, &bn_beta, &W1, &a1, &B1, &W2, &a2, &B2,
                         &W_ih, &b_ih, &b_hh, &W_out, &b_out, &wsf, &outp, &Nv };
        e = hipLaunchCooperativeKernel((void*)kFused, dim3(FG), dim3(128),
                                       args, 0, stream);
    }
    if (e != hipSuccess) {
        (void)hipGetLastError();          // clear sticky error, use r12 path
        kA_stats<<<dim3(NPART), dim3(320), 0, stream>>>(x, wsf, N / NPART);
        kB_setup<<<dim3(1), dim3(384), 0, stream>>>(bn_gamma, bn_beta, W1, a1, B1,
                                                    W2, a2, B2, b_ih, b_hh,
                                                    W_out, b_out, wsf, N);
        kC_main<<<dim3(N / 16), dim3(128), 0, stream>>>(x, wsf + PB_OFF, W_ih,
                                                        outp, N);
    }
}

// Round 15
// 338.998 us; speedup vs baseline: 2.3918x; 2.0903x over previous
//
#include <hip/hip_runtime.h>

#define F1260 1260
#define NPART 512                 // kA blocks (2/CU); plain-store partial slots
#define PB_OFF (NPART * 84)       // param block float offset (43008)

__device__ __forceinline__ float leakyf(float x) { return x >= 0.f ? x : 0.2f * x; }
__device__ __forceinline__ float eluf(float x) { return x > 0.f ? x : expm1f(x); }
__device__ __forceinline__ float sigmoidf(float x) { return 1.f / (1.f + __expf(-x)); }
// fast tanh: exact saturation (exp->inf => 1, exp->0 => -1), ~1e-6 abs err
__device__ __forceinline__ float tanh_fast(float x) { return 1.f - 2.f / (__expf(2.f * x) + 1.f); }

// ws float layout:
//   0 .. NPART*84 : per-block channel partials (b*84+ch = sum, b*84+42+ch = sq),
//                   plain stores (no atomics, no memset needed)
//   param block pb = ws + PB_OFF:
//       pb+0 scale[42]  pb+64 shift[42]  pb+128 adjn[7][49]
//       pb+512  WB[180][21] (stride 21 = 15.1 KB, sL1D-fits; r10-verified kC win)
//       pb+4832 bias[84]  pb+4928 Wout[147]  pb+5078 bout[7]
//
// SESSION CONSTRAINTS (measured, r0-r14):
//  * fill (harness ws-poison, 660 MB) ~95 us @87% HBM peak -- fixed cost.
//  * kA ~100 us: HBM-bound against the fill's dirty-line drain (825 MB
//    combined / ~7 TB/s); invariant to occupancy/grid/atomics (r5-r12).
//  * kC ~94 us: latency-bound @37% VALUBusy; occupancy x2 null (r9),
//    pipelining x3 negative (r2/r3/r8), xT streaming negative (r11),
//    cooperative fusion x2 negative (r13/r14 -- codegen loses the batched
//    gather; FETCH drop to 170 MB verified but issue rate collapses 5x).
//  * r11: never build big ws-resident x copies -- kC's gather rides the L3
//    residue of kA's read (FETCH 84 MB of a 165 MB input).

// ---------------- kA: BN stats, float4-coalesced, 512 blocks ----------------
__global__ __launch_bounds__(320) void kA_stats(const float* __restrict__ x,
                                                float* __restrict__ ws, int rows) {
    __shared__ float fs[1260], fq[1260];
    const int t = threadIdx.x;
    const int n0 = blockIdx.x * rows;
    if (t < 315) {
        const int f0 = t * 4;
        float s0 = 0.f, s1 = 0.f, s2 = 0.f, s3 = 0.f;
        float q0 = 0.f, q1 = 0.f, q2 = 0.f, q3 = 0.f;
#pragma unroll 16
        for (int i = 0; i < rows; ++i) {
            const float4 a = *(const float4*)(x + (size_t)(n0 + i) * F1260 + f0);
            s0 += a.x; q0 += a.x * a.x;
            s1 += a.y; q1 += a.y * a.y;
            s2 += a.z; q2 += a.z * a.z;
            s3 += a.w; q3 += a.w * a.w;
        }
        fs[f0 + 0] = s0; fq[f0 + 0] = q0;
        fs[f0 + 1] = s1; fq[f0 + 1] = q1;
        fs[f0 + 2] = s2; fq[f0 + 2] = q2;
        fs[f0 + 3] = s3; fq[f0 + 3] = q3;
    }
    __syncthreads();
    // channel ch = v*6 + c aggregates flat f = c*210 + tt*7 + v over tt
    if (t < 42) {
        const int v = t / 6, c = t % 6;
        float s = 0.f, q = 0.f;
#pragma unroll
        for (int tt = 0; tt < 30; ++tt) {
            const int f = c * 210 + tt * 7 + v;
            s += fs[f];
            q += fq[f];
        }
        ws[blockIdx.x * 84 + t] = s;
        ws[blockIdx.x * 84 + 42 + t] = q;
    }
}

// ---------------- kB: finalize BN, adjacency norm, weight folds ----------------
__global__ __launch_bounds__(384) void kB_setup(
        const float* __restrict__ bn_gamma, const float* __restrict__ bn_beta,
        const float* __restrict__ W1, const float* __restrict__ a1, const float* __restrict__ B1,
        const float* __restrict__ W2, const float* __restrict__ a2, const float* __restrict__ B2,
        const float* __restrict__ b_ih, const float* __restrict__ b_hh,
        const float* __restrict__ W_out, const float* __restrict__ b_out,
        float* __restrict__ ws, int N) {
    __shared__ float red[336];
    const int t = threadIdx.x;
    float* pb = ws + PB_OFF;
    const int HH[6] = {0, 3, 6, 10, 13, 16};
    const int EH[6] = {0, 3, 6, 0, 3, 6};

    // stage 1: 336 threads = part(0..3) x slot(0..83); each sums 128 blocks
    if (t < 336) {
        const int part = t / 84, slot = t - part * 84;
        const int b0 = part * (NPART / 4);
        float s = 0.f;
#pragma unroll 8
        for (int b = 0; b < NPART / 4; ++b) s += ws[(size_t)(b0 + b) * 84 + slot];
        red[t] = s;
    }
    __syncthreads();
    // stage 2: finalize per-channel BN scale/shift
    if (t < 42) {
        const float s = red[t] + red[84 + t] + red[168 + t] + red[252 + t];
        const float q = red[42 + t] + red[126 + t] + red[210 + t] + red[294 + t];
        const float cnt = 30.f * (float)N;
        const float mean = s / cnt;
        const float var = q / cnt - mean * mean;
        const float sc = bn_gamma[t] * rsqrtf(var + 1e-5f);
        pb[t] = sc;
        pb[64 + t] = bn_beta[t] - mean * sc;
    }
    // normalized adjacency: 6 GAT1 heads + GAT2 head0
    if (t >= 64 && t < 71) {
        const int idx = t - 64;
        const float* Bp = (idx < 6) ? (B1 + HH[idx] * 49) : B2;
        float* op = pb + 128 + idx * 49;
        float adj[49];
        for (int i = 0; i < 49; ++i) adj[i] = Bp[i];
        for (int i = 0; i < 7; ++i) adj[i * 8] += 1.f;
        float mn = adj[0], mx = adj[0];
        for (int i = 1; i < 49; ++i) { mn = fminf(mn, adj[i]); mx = fmaxf(mx, adj[i]); }
        const float inv = 1.f / (mx - mn);
        float rinv[7];
        for (int i = 0; i < 7; ++i) {
            float rs = 0.f;
            for (int j = 0; j < 7; ++j) { adj[i * 7 + j] = (adj[i * 7 + j] - mn) * inv; rs += adj[i * 7 + j]; }
            rinv[i] = rsqrtf(rs);
        }
        for (int i = 0; i < 7; ++i)
            for (int j = 0; j < 7; ++j)
                op[i * 7 + j] = adj[i * 7 + j] * rinv[i] * rinv[j];
    }
    // WB: fold a1 into W1 for the 6 live heads, repacked per-k, stride 21
    for (int task = t; task < 6 * 180; task += 384) {
        const int hh = task / 180, k = task % 180;
        const int h = HH[hh];
        const float* Wp = W1 + ((size_t)h * 180 + k) * 9;
        float si = 0.f, sj = 0.f;
        for (int e = 0; e < 9; ++e) {
            const float w = Wp[e];
            si += w * a1[h * 18 + e];
            sj += w * a1[h * 18 + 9 + e];
        }
        pb[512 + k * 21 + hh * 3 + 0] = si;
        pb[512 + k * 21 + hh * 3 + 1] = sj;
        pb[512 + k * 21 + hh * 3 + 2] = Wp[EH[hh]];
    }
    // WA2 slots (replicated per c): head 0 of l2, f=0 column kept
    if (t < 30) {
        const float* Wp = W2 + t * 10;
        float si = 0.f, sj = 0.f;
        for (int f = 0; f < 10; ++f) {
            const float w = Wp[f];
            si += w * a2[f];
            sj += w * a2[10 + f];
        }
        for (int c = 0; c < 6; ++c) {
            const int k = c * 30 + t;
            pb[512 + k * 21 + 18] = si;
            pb[512 + k * 21 + 19] = sj;
            pb[512 + k * 21 + 20] = Wp[0];
        }
    }
    if (t < 84) pb[4832 + t] = b_ih[t] + b_hh[t];
    if (t < 147) pb[4928 + t] = W_out[t];
    if (t < 7) pb[5078 + t] = b_out[t];
}

// ---------------- kC: fused dots + attention + LSTM + out ----------------
// r12-exact (best verified composite). 2-wave blocks (128 threads, 16
// samples), wave-local roles, res-overlay LDS (17836 B), WB stride 21
// (sL1D fit), direct stride-7 gather of x (L3-half-resident from kA's read).
// res-overlay per row (252 floats):
//   [0..126) s1 -> xs0[0..84) + h2t[84..126);  [126..252) g -> h1s[126..148)
#define RS 252
__global__ __launch_bounds__(128) void kC_main(const float* __restrict__ x,
        const float* __restrict__ pb, const float* __restrict__ Wih,
        float* __restrict__ outp, int N) {
    __shared__ __align__(16) float sm[4459];
    float* res  = sm;
    float* scsh = sm + 4032;
    float* adjL = sm + 4116;

    const int t = threadIdx.x;
    const int n0 = blockIdx.x * 16;
    const int v = (t >> 3) & 7;                // wave-local role 0..7
    const int nl = ((t >> 6) << 3) + (t & 7);  // sample row 0..15

    // ---- phase 0: params ----
    for (int i = t; i < 84; i += 128) scsh[i] = pb[i < 42 ? i : 22 + i];
    for (int i = t; i < 343; i += 128) adjL[i] = pb[128 + i];
    __syncthreads();

    // ---- phase 1: dots; thread = (v, nl), 112 active ----
    if (v < 7) {
        float s1[18];
#pragma unroll
        for (int i = 0; i < 18; ++i) s1[i] = 0.f;
        const float* xb = x + (size_t)(n0 + nl) * F1260 + v;
        const float* WB = pb + 512;
        for (int c = 0; c < 6; ++c) {
            const float sc = scsh[v * 6 + c];
            const float sh = scsh[42 + v * 6 + c];
            const float* xr = xb + c * 210;
            const float* wb = WB + (c * 30) * 21;
            float xv[30];
#pragma unroll
            for (int tt = 0; tt < 30; ++tt) xv[tt] = xr[tt * 7];   // batch loads
            float g0 = 0.f, g1 = 0.f, g2 = 0.f;
#pragma unroll
            for (int tt = 0; tt < 30; ++tt) {
                const float a = xv[tt] * sc + sh;
                const float* w = wb + tt * 21;                      // wave-uniform -> s_loads
#pragma unroll
                for (int q = 0; q < 18; ++q) s1[q] += a * w[q];
                g0 += a * w[18];
                g1 += a * w[19];
                g2 += a * w[20];
            }
            float* rp = res + nl * RS + 126 + (v * 6 + c) * 3;
            rp[0] = g0; rp[1] = g1; rp[2] = g2;
        }
#pragma unroll
        for (int q = 0; q < 18; ++q)
            res[nl * RS + v * 18 + q] = s1[q];
    }
    __syncthreads();

    // ---- phase 2: GAT1 heads; role hh = v ----
    // Pre-load by ALL threads (hh=6,7 read in-bounds garbage), then a barrier:
    // REQUIRED for cross-wave safety -- no overlay write may precede another
    // wave's s1 reads.
    const int hh = v;
    float si[7], sj[7], we[7];
#pragma unroll
    for (int vv = 0; vv < 7; ++vv) {
        const float* rp = res + nl * RS + vv * 18 + hh * 3;
        si[vv] = rp[0]; sj[vv] = rp[1]; we[vv] = rp[2];
    }
    __syncthreads();
    if (hh < 6) {
        float mxsj = sj[0];
#pragma unroll
        for (int j = 1; j < 7; ++j) mxsj = fmaxf(mxsj, sj[j]);
        float pr[7];
#pragma unroll
        for (int i = 0; i < 7; ++i) {
            const float m = leakyf(si[i] + mxsj);   // leaky monotonic -> row max
            float den = 0.f, num = 0.f;
#pragma unroll
            for (int j = 0; j < 7; ++j) {
                const float w = __expf(leakyf(si[i] + sj[j]) - m);
                den += w;
                num += w * we[j];
            }
            pr[i] = num / den;
        }
        const float* An = adjL + hh * 49;
#pragma unroll
        for (int i = 0; i < 7; ++i) {
            float r = 0.f;
#pragma unroll
            for (int k = 0; k < 7; ++k) r += An[i * 7 + k] * pr[k];
            res[nl * RS + hh * 7 + i] = eluf(r);        // xs0 overlay [0..42)
        }
    }
    // ---- phase 2b: GAT2 softmax-over-channels; role i = v (<7) ----
    if (v < 7) {
        const int i = v;
        float si2[6];
#pragma unroll
        for (int c = 0; c < 6; ++c)
            si2[c] = res[nl * RS + 126 + (i * 6 + c) * 3];
        float hc[6];
#pragma unroll
        for (int c = 0; c < 6; ++c) hc[c] = 0.f;
#pragma unroll
        for (int j = 0; j < 7; ++j) {
            float s[6];
            float m = -1e30f;
#pragma unroll
            for (int c = 0; c < 6; ++c) {
                const float* rp = res + nl * RS + 126 + (j * 6 + c) * 3;
                s[c] = leakyf(si2[c] + rp[1]);
                m = fmaxf(m, s[c]);
            }
            float den = 0.f;
#pragma unroll
            for (int c = 0; c < 6; ++c) { s[c] = __expf(s[c] - m); den += s[c]; }
            const float rd = 1.f / den;
#pragma unroll
            for (int c = 0; c < 6; ++c) {
                const float wh0 = res[nl * RS + 126 + (j * 6 + c) * 3 + 2];
                hc[c] += wh0 * s[c] * rd;
            }
        }
#pragma unroll
        for (int c = 0; c < 6; ++c)
            res[nl * RS + 84 + i * 6 + c] = hc[c];      // h2t overlay [84..126)
    }
    __syncthreads();

    // ---- phase 3: GAT2 adj multiply; role c = v (<6) ----
    if (v < 6) {
        const int c = v;
        const float* An2 = adjL + 6 * 49;
        float h[7];
#pragma unroll
        for (int u = 0; u < 7; ++u) h[u] = res[nl * RS + 84 + u * 6 + c];
#pragma unroll
        for (int vv = 0; vv < 7; ++vv) {
            float r = 0.f;
#pragma unroll
            for (int u = 0; u < 7; ++u) r += h[u] * An2[u * 7 + vv];
            res[nl * RS + 42 + c * 7 + vv] = eluf(r);   // xs0 overlay [42..84)
        }
    }
    __syncthreads();

    // ---- phase 4: LSTM step 0; role g8 = v, all threads; float4 reads ----
    {
        const int g8 = v;
        const float* bias = pb + 4832;
        const float4* xs4 = (const float4*)(res + nl * RS);
        for (int gi = g8; gi < 21; gi += 8) {
            float ga = bias[gi], gg = bias[42 + gi], go = bias[63 + gi];
            const float4* wa = (const float4*)(Wih + gi * 84);
            const float4* wg = (const float4*)(Wih + (42 + gi) * 84);
            const float4* wo = (const float4*)(Wih + (63 + gi) * 84);
#pragma unroll
            for (int k = 0; k < 21; ++k) {
                const float4 xv = xs4[k];
                const float4 a4 = wa[k];
                const float4 g4 = wg[k];
                const float4 o4 = wo[k];
                ga += xv.x * a4.x + xv.y * a4.y + xv.z * a4.z + xv.w * a4.w;
                gg += xv.x * g4.x + xv.y * g4.y + xv.z * g4.z + xv.w * g4.w;
                go += xv.x * o4.x + xv.y * o4.y + xv.z * o4.z + xv.w * o4.w;
            }
            const float c1 = sigmoidf(ga) * tanh_fast(gg);
            res[nl * RS + 126 + gi] = sigmoidf(go) * tanh_fast(c1);
        }
    }
    __syncthreads();

    // ---- phase 5: output projection; thread = n5*7+j, 112 active, coalesced ----
    if (t < 112) {
        const int n5 = t / 7, j = t - n5 * 7;
        const float* Wout = pb + 4928;
        float r = pb[5078 + j];
#pragma unroll
        for (int m = 0; m < 21; ++m) r += res[n5 * RS + 126 + m] * Wout[j * 21 + m];
        outp[(size_t)n0 * 7 + t] = r;
    }
}

extern "C" void kernel_launch(void* const* d_in, const int* in_sizes, int n_in,
                              void* d_out, int out_size, void* d_ws, size_t ws_size,
                              hipStream_t stream) {
    const int N = in_sizes[0] / F1260;

    const float* x        = (const float*)d_in[0];
    const float* bn_gamma = (const float*)d_in[1];
    const float* bn_beta  = (const float*)d_in[2];
    const float* W1       = (const float*)d_in[3];
    const float* a1       = (const float*)d_in[4];
    const float* B1       = (const float*)d_in[5];
    const float* W2       = (const float*)d_in[6];
    const float* a2       = (const float*)d_in[7];
    const float* B2       = (const float*)d_in[8];
    const float* W_ih     = (const float*)d_in[9];
    // d_in[10] = W_hh unused (h0 = 0 -> only LSTM step 0 matters)
    const float* b_ih     = (const float*)d_in[11];
    const float* b_hh     = (const float*)d_in[12];
    const float* W_out    = (const float*)d_in[13];
    const float* b_out    = (const float*)d_in[14];

    float* wsf = (float*)d_ws;

    // no memset dispatch: kA writes its partials with plain stores

    kA_stats<<<dim3(NPART), dim3(320), 0, stream>>>(x, wsf, N / NPART);
    kB_setup<<<dim3(1), dim3(384), 0, stream>>>(bn_gamma, bn_beta, W1, a1, B1,
                                                W2, a2, B2, b_ih, b_hh,
                                                W_out, b_out, wsf, N);
    kC_main<<<dim3(N / 16), dim3(128), 0, stream>>>(x, wsf + PB_OFF, W_ih,
                                                    (float*)d_out, N);
}